// Round 1
// baseline (405.935 us; speedup 1.0000x reference)
//
#include <hip/hip_runtime.h>
#include <hip/hip_bf16.h>
#include <stdint.h>

// Problem constants
#define Bq 1024
#define Dq 512
#define Nq 16
#define Hq 512
#define Mq (Bq*Nq)   // 16384

typedef short v8s  __attribute__((ext_vector_type(8)));
typedef float v16f __attribute__((ext_vector_type(16)));

typedef __attribute__((address_space(3))) unsigned int as3_u32;
typedef __attribute__((address_space(1))) const unsigned int as1_u32;

#define VMCNT(n) asm volatile("s_waitcnt vmcnt(" #n ")" ::: "memory")

__device__ __forceinline__ unsigned short f2bf(float f) {
  union { float f; unsigned u; } v; v.f = f;
  return (unsigned short)((v.u + 0x7fffu + ((v.u >> 16) & 1u)) >> 16);
}

// Xb[b*16+n][d] = bf16(x[b][d][n])
__global__ void k_transpose_x(const float* __restrict__ x, unsigned short* __restrict__ xb) {
  __shared__ float lds[Dq][Nq + 1];
  const int b = blockIdx.x;
  const float* xi = x + (size_t)b * Dq * Nq;
  const int t = threadIdx.x;
  for (int p = 0; p < (Dq*Nq)/256; ++p) {
    int i = t + p*256;
    lds[i >> 4][i & (Nq-1)] = xi[i];
  }
  __syncthreads();
  unsigned short* o = xb + (size_t)b * Nq * Dq;
  for (int p = 0; p < (Dq*Nq)/256; ++p) {
    int i = t + p*256;
    o[i] = f2bf(lds[i & (Dq-1)][i >> 9]);   // i = n*512 + d
  }
}

// One dispatch for all weight transposes: z=0 -> Ws1, z=1 -> Ws2, z>=2 -> Wc1[z-2]
__global__ void k_transpose_w(const float* __restrict__ Ws1, const float* __restrict__ Ws2,
                              const float* __restrict__ Wc1,
                              unsigned short* __restrict__ Ws1t, unsigned short* __restrict__ Ws2t,
                              unsigned short* __restrict__ Wc1t) {
  __shared__ float tile[32][33];
  const int z = blockIdx.z;
  const float* in;
  unsigned short* out;
  if (z == 0)      { in = Ws1; out = Ws1t; }
  else if (z == 1) { in = Ws2; out = Ws2t; }
  else             { in = Wc1 + (size_t)(z-2) * 512 * 512; out = Wc1t + (size_t)(z-2) * 512 * 512; }
  const int tx = threadIdx.x, ty = threadIdx.y;  // (32,8)
  const int c0 = blockIdx.x * 32, r0 = blockIdx.y * 32;
#pragma unroll
  for (int j = 0; j < 4; ++j)
    tile[ty + j*8][tx] = in[(size_t)(r0 + ty + j*8) * 512 + c0 + tx];
  __syncthreads();
#pragma unroll
  for (int j = 0; j < 4; ++j) {
    int c = c0 + ty + j*8;   // output row (input col)
    int r = r0 + tx;         // output col (input row)
    out[(size_t)c * 512 + r] = f2bf(tile[tx][ty + j*8]);
  }
}

// ---------------------------------------------------------------------------
// Old-structure GEMM, kept for the two shared-MLP GEMMs (MODE=0 only).
// ---------------------------------------------------------------------------
template<int MODE, int BM>
__global__ __launch_bounds__(256, 2)
void k_gemm(const unsigned short* __restrict__ A,
            const unsigned short* __restrict__ Bt,
            const float* __restrict__ bias,
            void* __restrict__ out_,
            const float* __restrict__ w2,
            int permute) {
  constexpr int BN = 128, BK = 32, KD = 512;
  constexpr int NI = (BM == 256) ? 4 : 2;
  constexpr int AG = BM / 16;
  constexpr int TG = AG + BN / 16;
  __shared__ __align__(16) unsigned short As[2][BM][BK];
  __shared__ __align__(16) unsigned short Bs[2][BN][BK];

  const int t = threadIdx.x;
  const int wave = t >> 6, lane = t & 63;
  const int wr = (BM == 256) ? wave : (wave >> 1);
  const int wc = (BM == 256) ? 0    : (wave & 1);
  const int l32 = lane & 31, kh0 = lane >> 5;
  const int bm = blockIdx.x * BM, bn = blockIdx.y * BN;
  const int z = blockIdx.z;

  const unsigned short* Bz = Bt + (size_t)z * KD * 512;
  const float* biasz = bias + (size_t)z * 512;

  const int lrow = lane >> 2;
  const int lslot = lane & 3;

  auto stage = [&](int buf, int kt) {
#pragma unroll
    for (int i = wave; i < TG; i += 4) {
      const int isA = (i < AG);
      const int r0 = (isA ? i : i - AG) * 16;
      const int row = r0 + lrow;
      const int cg = lslot ^ ((row >> 1) & 3);
      const unsigned short* g = isA ? &A [(size_t)(bm + row) * KD + kt*BK + cg*8]
                                    : &Bz[(size_t)(bn + row) * KD + kt*BK + cg*8];
      as3_u32* d = isA ? (as3_u32*)&As[buf][r0][0] : (as3_u32*)&Bs[buf][r0][0];
      __builtin_amdgcn_global_load_lds((as1_u32*)g, d, 16, 0, 0);
    }
  };

  v16f acc[2][NI] = {};

  stage(0, 0);
  __syncthreads();

  for (int kt = 0; kt < KD / BK; ++kt) {
    const int cur = kt & 1;
    if (kt + 1 < KD / BK) stage(cur ^ 1, kt + 1);

    v8s af[2][2], bf[NI][2];
#pragma unroll
    for (int mi = 0; mi < 2; ++mi) {
      int ra = wr*64 + mi*32 + l32;
#pragma unroll
      for (int kh = 0; kh < 2; ++kh) {
        int c = kh*2 + kh0;
        af[mi][kh] = *(const v8s*)&As[cur][ra][(c ^ ((ra >> 1) & 3)) * 8];
      }
    }
#pragma unroll
    for (int ni = 0; ni < NI; ++ni) {
      int rb = wc*64 + ni*32 + l32;
#pragma unroll
      for (int kh = 0; kh < 2; ++kh) {
        int c = kh*2 + kh0;
        bf[ni][kh] = *(const v8s*)&Bs[cur][rb][(c ^ ((rb >> 1) & 3)) * 8];
      }
    }
#pragma unroll
    for (int kh = 0; kh < 2; ++kh)
#pragma unroll
      for (int mi = 0; mi < 2; ++mi)
#pragma unroll
        for (int ni = 0; ni < NI; ++ni)
          acc[mi][ni] = __builtin_amdgcn_mfma_f32_32x32x16_bf16(af[mi][kh], bf[ni][kh], acc[mi][ni], 0, 0, 0);
    __syncthreads();
  }

  if (MODE == 0) {
    unsigned short* O = (unsigned short*)out_;
#pragma unroll
    for (int mi = 0; mi < 2; ++mi) {
#pragma unroll
      for (int ni = 0; ni < NI; ++ni) {
        int col = bn + wc*64 + ni*32 + l32;
        float bcol = biasz[col];
#pragma unroll
        for (int reg = 0; reg < 16; ++reg) {
          int rl = (reg & 3) + 8*(reg >> 2) + 4*kh0;
          int grow = bm + wr*64 + mi*32 + rl;
          int orow = permute ? ((grow & 15) * Bq + (grow >> 4)) : grow;
          float v = acc[mi][ni][reg] + bcol;
          v = v >= 0.f ? v : 0.1f * v;
          O[(size_t)orow * 512 + col] = f2bf(v);
        }
      }
    }
  } else {
    float* FL = (float*)out_;
    const float* w2z = w2 + (size_t)z * 512;
#pragma unroll
    for (int mi = 0; mi < 2; ++mi) {
#pragma unroll
      for (int reg = 0; reg < 16; ++reg) {
        int rl = (reg & 3) + 8*(reg >> 2) + 4*kh0;
        float s = 0.f;
#pragma unroll
        for (int ni = 0; ni < NI; ++ni) {
          int col = bn + ni*32 + l32;
          float v = acc[mi][ni][reg] + biasz[col];
          v = v >= 0.f ? v : 0.1f * v;
          s += v * w2z[col];
        }
#pragma unroll
        for (int off = 1; off < 32; off <<= 1)
          s += __shfl_xor(s, off, 64);
        if (l32 == 0) {
          int grow = bm + wave*64 + mi*32 + rl;
          atomicAdd(&FL[(size_t)grow * Nq + z], s);
        }
      }
    }
  }
}

// ---------------------------------------------------------------------------
// 8-phase 256x256 head-GEMM (T3+T4 counted vmcnt, T5 setprio, T2 swizzle).
// Per head z: FL[m][z] += sum_h lrelu(A@Wc1t[z] + bc1[z]) * Wc2[z][h]
// 512 threads = 8 waves (2M x 4N); per-wave 128x64 output; BK=64 in 2 k-halves.
// LDS [buf][khalf][A/B][256][32] = 128 KiB, double-buffered at K-tile granularity;
// k-half h of tile t+2 stages into buf[t&1] while tile t's other half computes.
// Counted vmcnt(8) at odd-phase ends only (never 0 in steady state): 8 loads/thread
// = the last 4 phases' staging stay in flight; the needed half was issued >=4
// phases earlier. Tail peels to vmcnt(4)/vmcnt(0) by exact outstanding count.
// ---------------------------------------------------------------------------
__global__ __launch_bounds__(512, 2)
void k_headgemm(const unsigned short* __restrict__ A,
                const unsigned short* __restrict__ Bt,
                const float* __restrict__ bias,
                float* __restrict__ FL,
                const float* __restrict__ w2) {
  __shared__ __align__(16) unsigned short sm[2][2][2][256][32];

  const int t = threadIdx.x;
  const int wave = t >> 6, lane = t & 63;
  const int wr = wave >> 2, wc = wave & 3;         // 2M x 4N
  const int l32 = lane & 31, kh0 = lane >> 5;
  const int bm = blockIdx.x * 256, bn = blockIdx.y * 256;
  const int z = blockIdx.z;

  const unsigned short* Bz = Bt + (size_t)z * Dq * 512;
  const float* biasz = bias + (size_t)z * 512;
  const float* w2z   = w2   + (size_t)z * 512;

  // Staging geometry: per issue a wave covers 16 rows x 64 B; lane -> row/slot.
  const int srow = wave*16 + (lane >> 2);          // 0..127 within a 128-row part
  const int sgc  = (lane & 3) ^ ((srow >> 1) & 3); // inverse-swizzled global chunk
  const unsigned short* aSrc = A  + (size_t)(bm + srow) * Dq + sgc*8;
  const unsigned short* bSrc = Bz + (size_t)(bn + srow) * Dq + sgc*8;

  auto stageA = [&](int T, int h) {
    const int buf = T & 1;
    const unsigned short* g = aSrc + T*64 + h*32;
#pragma unroll
    for (int part = 0; part < 2; ++part) {
      as3_u32* d = (as3_u32*)&sm[buf][h][0][part*128 + wave*16][0];
      __builtin_amdgcn_global_load_lds((as1_u32*)(g + (size_t)part*128*Dq), d, 16, 0, 0);
    }
  };
  auto stageB = [&](int T, int h) {
    const int buf = T & 1;
    const unsigned short* g = bSrc + T*64 + h*32;
#pragma unroll
    for (int part = 0; part < 2; ++part) {
      as3_u32* d = (as3_u32*)&sm[buf][h][1][part*128 + wave*16][0];
      __builtin_amdgcn_global_load_lds((as1_u32*)(g + (size_t)part*128*Dq), d, 16, 0, 0);
    }
  };

  // Fragment LDS byte offsets (within one [256][32] operand block), per k-parity.
  int offA[4][2], offB[2][2];
#pragma unroll
  for (int mi = 0; mi < 4; ++mi) {
    int r = wr*128 + mi*32 + l32;
#pragma unroll
    for (int par = 0; par < 2; ++par)
      offA[mi][par] = r*64 + (((par*2 + kh0) ^ ((r >> 1) & 3)) * 16);
  }
#pragma unroll
  for (int ni = 0; ni < 2; ++ni) {
    int r = wc*64 + ni*32 + l32;
#pragma unroll
    for (int par = 0; par < 2; ++par)
      offB[ni][par] = r*64 + (((par*2 + kh0) ^ ((r >> 1) & 3)) * 16);
  }

  v16f acc[4][2] = {};

  // Prologue: tile0 (both halves) + tile1 half0 = 12 loads/thread.
  stageA(0, 0); stageB(0, 0);
  stageA(0, 1); stageB(0, 1);
  stageA(1, 0); stageB(1, 0);
  VMCNT(8);                      // tile0 half0 landed; 8 in flight
  __builtin_amdgcn_s_barrier();

  for (int tt = 0; tt < 8; ++tt) {
    const int buf = tt & 1;
#pragma unroll
    for (int q = 0; q < 4; ++q) {
      const int h = q >> 1, par = q & 1;
      const char* baseA = (const char*)&sm[buf][h][0][0][0];
      const char* baseB = (const char*)&sm[buf][h][1][0][0];
      v8s af[4], bf[2];
#pragma unroll
      for (int mi = 0; mi < 4; ++mi) af[mi] = *(const v8s*)(baseA + offA[mi][par]);
#pragma unroll
      for (int ni = 0; ni < 2; ++ni) bf[ni] = *(const v8s*)(baseB + offB[ni][par]);

      // Staging: one half-tile operand (2 issues) per phase.
      if      (q == 0) { if (tt + 1 < 8) stageA(tt + 1, 1); }
      else if (q == 1) { if (tt + 1 < 8) stageB(tt + 1, 1); }
      else if (q == 2) { if (tt + 2 < 8) stageA(tt + 2, 0); }
      else             { if (tt + 2 < 8) stageB(tt + 2, 0); }

      __builtin_amdgcn_s_barrier();

      __builtin_amdgcn_s_setprio(1);
#pragma unroll
      for (int mi = 0; mi < 4; ++mi)
#pragma unroll
        for (int ni = 0; ni < 2; ++ni)
          acc[mi][ni] = __builtin_amdgcn_mfma_f32_32x32x16_bf16(af[mi], bf[ni], acc[mi][ni], 0, 0, 0);
      __builtin_amdgcn_s_setprio(0);

      // Counted-vmcnt checkpoints at odd-phase ends (protect the half read next).
      if (q == 1) {
        if (tt < 7) { VMCNT(8); } else { VMCNT(0); }
      } else if (q == 3) {
        if (tt < 6)       { VMCNT(8); }
        else if (tt == 6) { VMCNT(4); }
      }
      __builtin_amdgcn_s_barrier();
      __builtin_amdgcn_sched_barrier(0);   // keep next phase's ds_reads behind the barrier
    }
  }

  // Epilogue: lrelu + Wc2 dot + 32-lane reduce + atomic into FL[m][z].
#pragma unroll
  for (int mi = 0; mi < 4; ++mi) {
#pragma unroll
    for (int reg = 0; reg < 16; ++reg) {
      int rl = (reg & 3) + 8*(reg >> 2) + 4*kh0;
      float s = 0.f;
#pragma unroll
      for (int ni = 0; ni < 2; ++ni) {
        int col = bn + wc*64 + ni*32 + l32;
        float v = acc[mi][ni][reg] + biasz[col];
        v = v >= 0.f ? v : 0.1f * v;
        s += v * w2z[col];
      }
#pragma unroll
      for (int off = 1; off < 32; off <<= 1)
        s += __shfl_xor(s, off, 64);
      if (l32 == 0) {
        int grow = bm + wr*128 + mi*32 + rl;
        atomicAdd(&FL[(size_t)grow * Nq + z], s);
      }
    }
  }
}

// full_out[m][n] = FL[m][n] + bc2[n]; out[b][n] = sigmoid(full_out[n*B+b][n])
__global__ void k_final(const float* __restrict__ fl, const float* __restrict__ bc2,
                        float* __restrict__ out) {
  int i = blockIdx.x * 256 + threadIdx.x;
  int m = i >> 4, n = i & 15;
  float v = fl[i] + bc2[n];
  out[Mq + i] = v;
  if (n == (m >> 10)) {
    int b = m & (Bq - 1);
    out[b * Nq + n] = 1.f / (1.f + __expf(-v));
  }
}

extern "C" void kernel_launch(void* const* d_in, const int* in_sizes, int n_in,
                              void* d_out, int out_size, void* d_ws, size_t ws_size,
                              hipStream_t stream) {
  (void)in_sizes; (void)n_in; (void)out_size; (void)ws_size;
  const float* x   = (const float*)d_in[0];
  const float* Ws1 = (const float*)d_in[1];
  const float* bs1 = (const float*)d_in[2];
  const float* Ws2 = (const float*)d_in[3];
  const float* bs2 = (const float*)d_in[4];
  const float* Wc1 = (const float*)d_in[5];
  const float* bc1 = (const float*)d_in[6];
  const float* Wc2 = (const float*)d_in[7];
  const float* bc2 = (const float*)d_in[8];

  char* ws = (char*)d_ws;
  unsigned short* Xb   = (unsigned short*)(ws);
  unsigned short* Hbuf = (unsigned short*)(ws + (size_t)16*1024*1024);
  unsigned short* Sm   = (unsigned short*)(ws + (size_t)32*1024*1024);
  unsigned short* Ws1t = (unsigned short*)(ws + (size_t)48*1024*1024);
  unsigned short* Ws2t = (unsigned short*)(ws + (size_t)48*1024*1024 + 512*1024);
  unsigned short* Wc1t = (unsigned short*)(ws + (size_t)49*1024*1024);
  float*          FL   = (float*)         (ws + (size_t)57*1024*1024);

  hipMemsetAsync(FL, 0, (size_t)Mq * Nq * sizeof(float), stream);

  k_transpose_x<<<Bq, 256, 0, stream>>>(x, Xb);
  k_transpose_w<<<dim3(16,16,18), dim3(32,8), 0, stream>>>(Ws1, Ws2, Wc1, Ws1t, Ws2t, Wc1t);

  // shared MLP: H = lrelu(Xb@Ws1+bs1); Sm = lrelu(H@Ws2+bs2) in m = n*B+b row order
  k_gemm<0,128><<<dim3(128,4,1), 256, 0, stream>>>(Xb,   Ws1t, bs1, Hbuf, nullptr, 0);
  k_gemm<0,128><<<dim3(128,4,1), 256, 0, stream>>>(Hbuf, Ws2t, bs2, Sm,   nullptr, 1);
  // fused per-head GEMM + H-reduction into FL (8-phase 256x256, counted vmcnt)
  k_headgemm<<<dim3(64,2,16), 512, 0, stream>>>(Sm, Wc1t, bc1, FL, Wc2);

  k_final<<<(Mq*Nq)/256, 256, 0, stream>>>(FL, bc2, (float*)d_out);
}

// Round 2
// 334.535 us; speedup vs baseline: 1.2134x; 1.2134x over previous
//
#include <hip/hip_runtime.h>
#include <hip/hip_bf16.h>
#include <stdint.h>

// Problem constants
#define Bq 1024
#define Dq 512
#define Nq 16
#define Hq 512
#define Mq (Bq*Nq)   // 16384

typedef short v8s  __attribute__((ext_vector_type(8)));
typedef float v4f  __attribute__((ext_vector_type(4)));
typedef float v16f __attribute__((ext_vector_type(16)));

typedef __attribute__((address_space(3))) unsigned int as3_u32;
typedef __attribute__((address_space(1))) const unsigned int as1_u32;

#define VMCNT(n) asm volatile("s_waitcnt vmcnt(" #n ")" ::: "memory")

__device__ __forceinline__ unsigned short f2bf(float f) {
  union { float f; unsigned u; } v; v.f = f;
  return (unsigned short)((v.u + 0x7fffu + ((v.u >> 16) & 1u)) >> 16);
}

// Xb[b*16+n][d] = bf16(x[b][d][n])
__global__ void k_transpose_x(const float* __restrict__ x, unsigned short* __restrict__ xb) {
  __shared__ float lds[Dq][Nq + 1];
  const int b = blockIdx.x;
  const float* xi = x + (size_t)b * Dq * Nq;
  const int t = threadIdx.x;
  for (int p = 0; p < (Dq*Nq)/256; ++p) {
    int i = t + p*256;
    lds[i >> 4][i & (Nq-1)] = xi[i];
  }
  __syncthreads();
  unsigned short* o = xb + (size_t)b * Nq * Dq;
  for (int p = 0; p < (Dq*Nq)/256; ++p) {
    int i = t + p*256;
    o[i] = f2bf(lds[i & (Dq-1)][i >> 9]);   // i = n*512 + d
  }
}

// One dispatch for all weight transposes: z=0 -> Ws1, z=1 -> Ws2, z>=2 -> Wc1[z-2]
__global__ void k_transpose_w(const float* __restrict__ Ws1, const float* __restrict__ Ws2,
                              const float* __restrict__ Wc1,
                              unsigned short* __restrict__ Ws1t, unsigned short* __restrict__ Ws2t,
                              unsigned short* __restrict__ Wc1t) {
  __shared__ float tile[32][33];
  const int z = blockIdx.z;
  const float* in;
  unsigned short* out;
  if (z == 0)      { in = Ws1; out = Ws1t; }
  else if (z == 1) { in = Ws2; out = Ws2t; }
  else             { in = Wc1 + (size_t)(z-2) * 512 * 512; out = Wc1t + (size_t)(z-2) * 512 * 512; }
  const int tx = threadIdx.x, ty = threadIdx.y;  // (32,8)
  const int c0 = blockIdx.x * 32, r0 = blockIdx.y * 32;
#pragma unroll
  for (int j = 0; j < 4; ++j)
    tile[ty + j*8][tx] = in[(size_t)(r0 + ty + j*8) * 512 + c0 + tx];
  __syncthreads();
#pragma unroll
  for (int j = 0; j < 4; ++j) {
    int c = c0 + ty + j*8;   // output row (input col)
    int r = r0 + tx;         // output col (input row)
    out[(size_t)c * 512 + r] = f2bf(tile[tx][ty + j*8]);
  }
}

// ---------------------------------------------------------------------------
// Old-structure GEMM, kept for the two shared-MLP GEMMs (MODE=0 only).
// ---------------------------------------------------------------------------
template<int MODE, int BM>
__global__ __launch_bounds__(256, 2)
void k_gemm(const unsigned short* __restrict__ A,
            const unsigned short* __restrict__ Bt,
            const float* __restrict__ bias,
            void* __restrict__ out_,
            const float* __restrict__ w2,
            int permute) {
  constexpr int BN = 128, BK = 32, KD = 512;
  constexpr int NI = (BM == 256) ? 4 : 2;
  constexpr int AG = BM / 16;
  constexpr int TG = AG + BN / 16;
  __shared__ __align__(16) unsigned short As[2][BM][BK];
  __shared__ __align__(16) unsigned short Bs[2][BN][BK];

  const int t = threadIdx.x;
  const int wave = t >> 6, lane = t & 63;
  const int wr = (BM == 256) ? wave : (wave >> 1);
  const int wc = (BM == 256) ? 0    : (wave & 1);
  const int l32 = lane & 31, kh0 = lane >> 5;
  const int bm = blockIdx.x * BM, bn = blockIdx.y * BN;
  const int z = blockIdx.z;

  const unsigned short* Bz = Bt + (size_t)z * KD * 512;
  const float* biasz = bias + (size_t)z * 512;

  const int lrow = lane >> 2;
  const int lslot = lane & 3;

  auto stage = [&](int buf, int kt) {
#pragma unroll
    for (int i = wave; i < TG; i += 4) {
      const int isA = (i < AG);
      const int r0 = (isA ? i : i - AG) * 16;
      const int row = r0 + lrow;
      const int cg = lslot ^ ((row >> 1) & 3);
      const unsigned short* g = isA ? &A [(size_t)(bm + row) * KD + kt*BK + cg*8]
                                    : &Bz[(size_t)(bn + row) * KD + kt*BK + cg*8];
      as3_u32* d = isA ? (as3_u32*)&As[buf][r0][0] : (as3_u32*)&Bs[buf][r0][0];
      __builtin_amdgcn_global_load_lds((as1_u32*)g, d, 16, 0, 0);
    }
  };

  v16f acc[2][NI] = {};

  stage(0, 0);
  __syncthreads();

  for (int kt = 0; kt < KD / BK; ++kt) {
    const int cur = kt & 1;
    if (kt + 1 < KD / BK) stage(cur ^ 1, kt + 1);

    v8s af[2][2], bf[NI][2];
#pragma unroll
    for (int mi = 0; mi < 2; ++mi) {
      int ra = wr*64 + mi*32 + l32;
#pragma unroll
      for (int kh = 0; kh < 2; ++kh) {
        int c = kh*2 + kh0;
        af[mi][kh] = *(const v8s*)&As[cur][ra][(c ^ ((ra >> 1) & 3)) * 8];
      }
    }
#pragma unroll
    for (int ni = 0; ni < NI; ++ni) {
      int rb = wc*64 + ni*32 + l32;
#pragma unroll
      for (int kh = 0; kh < 2; ++kh) {
        int c = kh*2 + kh0;
        bf[ni][kh] = *(const v8s*)&Bs[cur][rb][(c ^ ((rb >> 1) & 3)) * 8];
      }
    }
#pragma unroll
    for (int kh = 0; kh < 2; ++kh)
#pragma unroll
      for (int mi = 0; mi < 2; ++mi)
#pragma unroll
        for (int ni = 0; ni < NI; ++ni)
          acc[mi][ni] = __builtin_amdgcn_mfma_f32_32x32x16_bf16(af[mi][kh], bf[ni][kh], acc[mi][ni], 0, 0, 0);
    __syncthreads();
  }

  if (MODE == 0) {
    unsigned short* O = (unsigned short*)out_;
#pragma unroll
    for (int mi = 0; mi < 2; ++mi) {
#pragma unroll
      for (int ni = 0; ni < NI; ++ni) {
        int col = bn + wc*64 + ni*32 + l32;
        float bcol = biasz[col];
#pragma unroll
        for (int reg = 0; reg < 16; ++reg) {
          int rl = (reg & 3) + 8*(reg >> 2) + 4*kh0;
          int grow = bm + wr*64 + mi*32 + rl;
          int orow = permute ? ((grow & 15) * Bq + (grow >> 4)) : grow;
          float v = acc[mi][ni][reg] + bcol;
          v = v >= 0.f ? v : 0.1f * v;
          O[(size_t)orow * 512 + col] = f2bf(v);
        }
      }
    }
  } else {
    float* FL = (float*)out_;
    const float* w2z = w2 + (size_t)z * 512;
#pragma unroll
    for (int mi = 0; mi < 2; ++mi) {
#pragma unroll
      for (int reg = 0; reg < 16; ++reg) {
        int rl = (reg & 3) + 8*(reg >> 2) + 4*kh0;
        float s = 0.f;
#pragma unroll
        for (int ni = 0; ni < NI; ++ni) {
          int col = bn + ni*32 + l32;
          float v = acc[mi][ni][reg] + biasz[col];
          v = v >= 0.f ? v : 0.1f * v;
          s += v * w2z[col];
        }
#pragma unroll
        for (int off = 1; off < 32; off <<= 1)
          s += __shfl_xor(s, off, 64);
        if (l32 == 0) {
          int grow = bm + wave*64 + mi*32 + rl;
          atomicAdd(&FL[(size_t)grow * Nq + z], s);
        }
      }
    }
  }
}

// ---------------------------------------------------------------------------
// Head-GEMM, m201 geometry: 256x256 tile, BK=64, 8 waves (2M x 4N), per-wave
// 128x64 output via 16x16x32 MFMA -> acc[8][4] f32x4 (128 VGPR).
// Reads/MFMA = 24/64 = 0.375 wave-b128 per MFMA (was 0.75 -> LDS-BW-bound).
// LDS [buf][khalf][op][256][32] bf16 = 128 KiB; 64B rows; chunk swizzle
// c ^ ((row>>1)&3) on both the pre-swizzled global source and the read.
// 4 phases/tile x 16 MFMA; staging granule (tile,half,op) = 2 gload_lds/wave;
// counted vmcnt(4) at ends of p1/p3 only (never 0 until the tail).
// ---------------------------------------------------------------------------
__global__ __launch_bounds__(512, 2)
void k_headgemm(const unsigned short* __restrict__ A,
                const unsigned short* __restrict__ Bt,
                const float* __restrict__ bias,
                float* __restrict__ FL,
                const float* __restrict__ w2) {
  __shared__ __align__(16) unsigned short sm[2][2][2][256][32];

  const int t = threadIdx.x;
  const int wave = t >> 6, lane = t & 63;
  const int wr = wave >> 2, wc = wave & 3;         // 2M x 4N
  const int bm = blockIdx.x * 256, bn = blockIdx.y * 256;
  const int z = blockIdx.z;

  const unsigned short* Bz = Bt + (size_t)z * Dq * 512;
  const float* biasz = bias + (size_t)z * 512;
  const float* w2z   = w2   + (size_t)z * 512;

  // Staging: per (tile,half,op) a wave does 2 issues of 1KB = 16 rows x 64B.
  // Lane l -> row (l>>2), 16B slot (l&3); source chunk = slot ^ ((row>>1)&3).
  const int sr = lane >> 2;
  const int sc = (lane & 3) ^ ((sr >> 1) & 3);
  const unsigned short* aSrc = A  + (size_t)(bm + wave*32 + sr) * Dq + sc*8;
  const unsigned short* bSrc = Bz + (size_t)(bn + wave*32 + sr) * Dq + sc*8;

  auto stage = [&](int T, int h, int op) {
    const unsigned short* src = (op == 0 ? aSrc : bSrc) + T*64 + h*32;
#pragma unroll
    for (int j = 0; j < 2; ++j) {
      as3_u32* d = (as3_u32*)&sm[T & 1][h][op][wave*32 + j*16][0];
      __builtin_amdgcn_global_load_lds((as1_u32*)(src + (size_t)j*16*Dq), d, 16, 0, 0);
    }
  };

  // Fragment read offsets (bytes within one [256][32] op block).
  // A-frag mi': row wr*128+mi'*16+(l&15), chunk (l>>4)^(row>>1 &3).
  const int fr = lane & 15, fq = lane >> 4;
  const int swz = ((fq ^ ((fr >> 1) & 3)) * 16);
  const int offA0 = (wr*128 + fr) * 64 + swz;
  const int offB0 = (wc*64  + fr) * 64 + swz;

  v4f acc[8][4] = {};

  // Prologue: stage tile 0 fully (8 issues/wave).
  stage(0, 0, 0); stage(0, 0, 1);
  stage(0, 1, 0); stage(0, 1, 1);
  VMCNT(4);                      // tile0 half0 landed; half1 (4) in flight
  __builtin_amdgcn_s_barrier();
  __builtin_amdgcn_sched_barrier(0);

#pragma unroll 2
  for (int tt = 0; tt < 8; ++tt) {
    const char* bA0 = (const char*)&sm[tt & 1][0][0][0][0];
    const char* bB0 = (const char*)&sm[tt & 1][0][1][0][0];
    const char* bA1 = (const char*)&sm[tt & 1][1][0][0][0];
    const char* bB1 = (const char*)&sm[tt & 1][1][1][0][0];
    v8s af[4], bf[4];

    // ---- p0: half0, mh=0 --------------------------------------------------
#pragma unroll
    for (int i = 0; i < 4; ++i) af[i] = *(const v8s*)(bA0 + offA0 + i*1024);
#pragma unroll
    for (int i = 0; i < 4; ++i) bf[i] = *(const v8s*)(bB0 + offB0 + i*1024);
    if (tt + 1 < 8) stage(tt + 1, 0, 0);
    __builtin_amdgcn_s_barrier();
    __builtin_amdgcn_s_setprio(1);
#pragma unroll
    for (int mi = 0; mi < 4; ++mi)
#pragma unroll
      for (int ni = 0; ni < 4; ++ni)
        acc[mi][ni] = __builtin_amdgcn_mfma_f32_16x16x32_bf16(af[mi], bf[ni], acc[mi][ni], 0, 0, 0);
    __builtin_amdgcn_s_setprio(0);
    __builtin_amdgcn_s_barrier();

    // ---- p1: half0, mh=1 (B kept in regs) ---------------------------------
#pragma unroll
    for (int i = 0; i < 4; ++i) af[i] = *(const v8s*)(bA0 + offA0 + (4 + i)*1024);
    if (tt + 1 < 8) stage(tt + 1, 0, 1);
    __builtin_amdgcn_s_barrier();
    __builtin_amdgcn_s_setprio(1);
#pragma unroll
    for (int mi = 0; mi < 4; ++mi)
#pragma unroll
      for (int ni = 0; ni < 4; ++ni)
        acc[4 + mi][ni] = __builtin_amdgcn_mfma_f32_16x16x32_bf16(af[mi], bf[ni], acc[4 + mi][ni], 0, 0, 0);
    __builtin_amdgcn_s_setprio(0);
    if (tt < 7) { VMCNT(4); } else { VMCNT(0); }   // (tt,h1) landed for p2
    __builtin_amdgcn_s_barrier();
    __builtin_amdgcn_sched_barrier(0);

    // ---- p2: half1, mh=0 --------------------------------------------------
#pragma unroll
    for (int i = 0; i < 4; ++i) af[i] = *(const v8s*)(bA1 + offA0 + i*1024);
#pragma unroll
    for (int i = 0; i < 4; ++i) bf[i] = *(const v8s*)(bB1 + offB0 + i*1024);
    if (tt + 1 < 8) stage(tt + 1, 1, 0);
    __builtin_amdgcn_s_barrier();
    __builtin_amdgcn_s_setprio(1);
#pragma unroll
    for (int mi = 0; mi < 4; ++mi)
#pragma unroll
      for (int ni = 0; ni < 4; ++ni)
        acc[mi][ni] = __builtin_amdgcn_mfma_f32_16x16x32_bf16(af[mi], bf[ni], acc[mi][ni], 0, 0, 0);
    __builtin_amdgcn_s_setprio(0);
    __builtin_amdgcn_s_barrier();

    // ---- p3: half1, mh=1 --------------------------------------------------
#pragma unroll
    for (int i = 0; i < 4; ++i) af[i] = *(const v8s*)(bA1 + offA0 + (4 + i)*1024);
    if (tt + 1 < 8) stage(tt + 1, 1, 1);
    __builtin_amdgcn_s_barrier();
    __builtin_amdgcn_s_setprio(1);
#pragma unroll
    for (int mi = 0; mi < 4; ++mi)
#pragma unroll
      for (int ni = 0; ni < 4; ++ni)
        acc[4 + mi][ni] = __builtin_amdgcn_mfma_f32_16x16x32_bf16(af[mi], bf[ni], acc[4 + mi][ni], 0, 0, 0);
    __builtin_amdgcn_s_setprio(0);
    if (tt < 7) { VMCNT(4); }                     // (tt+1,h0) landed for next p0
    __builtin_amdgcn_s_barrier();
    __builtin_amdgcn_sched_barrier(0);
  }

  // Epilogue: lrelu + Wc2 dot over this wave's 64 cols, 16-lane reduce,
  // atomicAdd partial into FL[m][z].  D-frag: row=(l>>4)*4+reg, col=l&15.
  float bcol[4], wcol[4];
#pragma unroll
  for (int ni = 0; ni < 4; ++ni) {
    int col = bn + wc*64 + ni*16 + fr;
    bcol[ni] = biasz[col];
    wcol[ni] = w2z[col];
  }
#pragma unroll
  for (int mi = 0; mi < 8; ++mi) {
#pragma unroll
    for (int reg = 0; reg < 4; ++reg) {
      float s = 0.f;
#pragma unroll
      for (int ni = 0; ni < 4; ++ni) {
        float v = acc[mi][ni][reg] + bcol[ni];
        v = v >= 0.f ? v : 0.1f * v;
        s += v * wcol[ni];
      }
#pragma unroll
      for (int off = 1; off < 16; off <<= 1)
        s += __shfl_xor(s, off, 64);
      if (fr == 0) {
        int grow = bm + wr*128 + mi*16 + fq*4 + reg;
        atomicAdd(&FL[(size_t)grow * Nq + z], s);
      }
    }
  }
}

// full_out[m][n] = FL[m][n] + bc2[n]; out[b][n] = sigmoid(full_out[n*B+b][n])
__global__ void k_final(const float* __restrict__ fl, const float* __restrict__ bc2,
                        float* __restrict__ out) {
  int i = blockIdx.x * 256 + threadIdx.x;
  int m = i >> 4, n = i & 15;
  float v = fl[i] + bc2[n];
  out[Mq + i] = v;
  if (n == (m >> 10)) {
    int b = m & (Bq - 1);
    out[b * Nq + n] = 1.f / (1.f + __expf(-v));
  }
}

extern "C" void kernel_launch(void* const* d_in, const int* in_sizes, int n_in,
                              void* d_out, int out_size, void* d_ws, size_t ws_size,
                              hipStream_t stream) {
  (void)in_sizes; (void)n_in; (void)out_size; (void)ws_size;
  const float* x   = (const float*)d_in[0];
  const float* Ws1 = (const float*)d_in[1];
  const float* bs1 = (const float*)d_in[2];
  const float* Ws2 = (const float*)d_in[3];
  const float* bs2 = (const float*)d_in[4];
  const float* Wc1 = (const float*)d_in[5];
  const float* bc1 = (const float*)d_in[6];
  const float* Wc2 = (const float*)d_in[7];
  const float* bc2 = (const float*)d_in[8];

  char* ws = (char*)d_ws;
  unsigned short* Xb   = (unsigned short*)(ws);
  unsigned short* Hbuf = (unsigned short*)(ws + (size_t)16*1024*1024);
  unsigned short* Sm   = (unsigned short*)(ws + (size_t)32*1024*1024);
  unsigned short* Ws1t = (unsigned short*)(ws + (size_t)48*1024*1024);
  unsigned short* Ws2t = (unsigned short*)(ws + (size_t)48*1024*1024 + 512*1024);
  unsigned short* Wc1t = (unsigned short*)(ws + (size_t)49*1024*1024);
  float*          FL   = (float*)         (ws + (size_t)57*1024*1024);

  hipMemsetAsync(FL, 0, (size_t)Mq * Nq * sizeof(float), stream);

  k_transpose_x<<<Bq, 256, 0, stream>>>(x, Xb);
  k_transpose_w<<<dim3(16,16,18), dim3(32,8), 0, stream>>>(Ws1, Ws2, Wc1, Ws1t, Ws2t, Wc1t);

  // shared MLP: H = lrelu(Xb@Ws1+bs1); Sm = lrelu(H@Ws2+bs2) in m = n*B+b row order
  k_gemm<0,128><<<dim3(128,4,1), 256, 0, stream>>>(Xb,   Ws1t, bs1, Hbuf, nullptr, 0);
  k_gemm<0,128><<<dim3(128,4,1), 256, 0, stream>>>(Hbuf, Ws2t, bs2, Sm,   nullptr, 1);
  // fused per-head GEMM + H-reduction into FL (m201 geometry, counted vmcnt)
  k_headgemm<<<dim3(64,2,16), 512, 0, stream>>>(Sm, Wc1t, bc1, FL, Wc2);

  k_final<<<(Mq*Nq)/256, 256, 0, stream>>>(FL, bc2, (float*)d_out);
}